// Round 3
// baseline (691.606 us; speedup 1.0000x reference)
//
#include <hip/hip_runtime.h>

// Causal bag-of-words: out[b,t,c] = mean(x[b,0..t,c]).
// Single-pass chunked scan with decoupled look-back (rocPRIM/CUB style).
// B=8, T=8192, C=512 row-major, fp32.
//
// Tiles: (b, chunk) with L=32 rows; NTILE = 8*256 = 2048 tiles.
// Block = 256 threads: thread (h = tid>>7, c4 = tid&127) owns 16 rows of one
// float4 column; local prefix kept in 16 VGPR-resident float4s (x read ONCE).
// Ticket counter orders tiles -> look-back only waits on earlier tickets
// (deadlock-free for any dispatch order / occupancy).

typedef float v4f __attribute__((ext_vector_type(4)));

constexpr int B = 8, T = 8192, C4 = 128;
constexpr int L = 32;           // rows per tile
constexpr int NCH = T / L;      // 256 tiles per batch
constexpr int NTILE = B * NCH;  // 2048
constexpr int RPT = 16;         // rows per thread

// ws layout (bytes):
//   [0]        unsigned ticket
//   [256]      unsigned flags[NTILE]        (0=invalid, 1=agg ready, 2=inclusive ready)
//   [16K]      v4f agg[NTILE][C4]           (4 MiB)
//   [16K+4M]   v4f inc[NTILE][C4]           (4 MiB)
constexpr size_t FLAGS_OFF = 256;
constexpr size_t AGG_OFF   = 16 * 1024;
constexpr size_t INC_OFF   = AGG_OFF + (size_t)NTILE * C4 * sizeof(v4f);

__global__ __launch_bounds__(256) void cbow_init(unsigned* ws) {
    const int i = blockIdx.x * 256 + threadIdx.x;   // grid covers NTILE
    if (i == 0) ws[0] = 0u;                          // ticket
    unsigned* flags = ws + FLAGS_OFF / 4;
    if (i < NTILE) flags[i] = 0u;
}

__global__ __launch_bounds__(256) void cbow_scan_onepass(
        const v4f* __restrict__ x, v4f* __restrict__ out,
        unsigned char* __restrict__ wsb) {
    unsigned* ticket = (unsigned*)wsb;
    unsigned* flags  = (unsigned*)(wsb + FLAGS_OFF);
    v4f* agg = (v4f*)(wsb + AGG_OFF);
    v4f* inc = (v4f*)(wsb + INC_OFF);

    __shared__ v4f s_sum[2][C4];
    __shared__ v4f s_excl[C4];
    __shared__ int s_tile;
    __shared__ int s_state;

    const int tid = threadIdx.x;
    if (tid == 0) s_tile = (int)atomicAdd(ticket, 1u);
    __syncthreads();
    const int tile  = s_tile;
    const int b     = tile >> 8;        // NCH = 256
    const int chunk = tile & (NCH - 1);
    const int c4    = tid & (C4 - 1);
    const int h     = tid >> 7;         // 0 or 1
    const int t0    = chunk * L + h * RPT;  // first absolute row for this thread

    // ---- load 16 rows, build local running prefix in registers ----
    const v4f* p = x + (size_t)(b * T + t0) * C4 + c4;
    v4f pref[RPT];
    pref[0] = __builtin_nontemporal_load(p);
#pragma unroll
    for (int r = 1; r < RPT; ++r)
        pref[r] = pref[r - 1] + __builtin_nontemporal_load(p + (size_t)r * C4);

    s_sum[h][c4] = pref[RPT - 1];
    __syncthreads();

    // ---- publish tile aggregate ----
    v4f aggv = s_sum[0][c4] + s_sum[1][c4];   // valid for tid < C4 use below
    if (chunk > 0) {
        if (tid < C4) agg[(size_t)tile * C4 + c4] = aggv;
        __syncthreads();                        // payload done before flag
        if (tid == 0) __atomic_store_n(&flags[tile], 1u, __ATOMIC_RELEASE);
    }

    // ---- decoupled look-back ----
    v4f excl = 0.f;
    if (chunk > 0) {
        int j = tile - 1;   // same b (chunk > 0)
        for (;;) {
            if (tid == 0) {
                unsigned f;
                for (;;) {
                    f = __atomic_load_n(&flags[j], __ATOMIC_RELAXED);
                    if (f == 1u || f == 2u) break;
                    __builtin_amdgcn_s_sleep(1);
                }
                __atomic_thread_fence(__ATOMIC_ACQUIRE);
                s_state = (int)f;
            }
            __syncthreads();
            const int st = s_state;
            __syncthreads();
            if (tid < C4) {
                const v4f* pay = (st == 2) ? inc + (size_t)j * C4
                                           : agg + (size_t)j * C4;
                excl += pay[c4];
            }
            if (st == 2) break;
            --j;
        }
    }

    // ---- publish inclusive prefix, share exclusive with block ----
    if (tid < C4) {
        inc[(size_t)tile * C4 + c4] = excl + aggv;
        s_excl[c4] = excl;
    }
    __syncthreads();
    if (tid == 0) __atomic_store_n(&flags[tile], 2u, __ATOMIC_RELEASE);

    // ---- write outputs ----
    const v4f base = s_excl[c4] + (h ? s_sum[0][c4] : (v4f)0.f);
    v4f* o = out + (size_t)(b * T + t0) * C4 + c4;
#pragma unroll
    for (int r = 0; r < RPT; ++r) {
        const float inv = __builtin_amdgcn_rcpf((float)(t0 + r + 1));
        __builtin_nontemporal_store((base + pref[r]) * inv, o + (size_t)r * C4);
    }
}

extern "C" void kernel_launch(void* const* d_in, const int* in_sizes, int n_in,
                              void* d_out, int out_size, void* d_ws, size_t ws_size,
                              hipStream_t stream) {
    const v4f* x   = (const v4f*)d_in[0];
    v4f*       out = (v4f*)d_out;

    cbow_init<<<NTILE / 256, 256, 0, stream>>>((unsigned*)d_ws);
    cbow_scan_onepass<<<NTILE, 256, 0, stream>>>(x, out, (unsigned char*)d_ws);
}